// Round 4
// baseline (495.696 us; speedup 1.0000x reference)
//
#include <hip/hip_runtime.h>
#include <math.h>

// Problem constants (from reference setup_inputs): B=64, T=2048, D=768, fp32.
#define B_ 64
#define T_ 2048
#define D_ 768
#define D4_ 192          // float4 per frame
#define S_ 32            // strided sub-reductions per row -> 64*32 = 2048 blocks
#define EPS_ 1e-5f

// count[b] = clip(floor(lens*T)+1, 1, T); when length == 1.0 exactly the
// reference takes the FULL mean over T frames (the jnp.where branch).
static __device__ __forceinline__ int row_count(float lenfrac) {
    float length = lenfrac * (float)T_;
    if (length == 1.0f) return T_;
    int c = (int)floorf(length) + 1;
    if (c < 1) c = 1;
    if (c > T_) c = T_;
    return c;
}

// ---- Kernel P: per-(row, s) STRIDED partial column sums over valid frames ----
// Block (b, s) sums frames t = s, s+S_, s+2S_, ... (< count[b]).
// Strided assignment -> every block does ~count/S_ frames: perfect balance
// regardless of the lens distribution. grid (B_, S_), 192 threads; thread t
// owns float4 column d4 = t (one frame = 192 float4 = 3 KB; each wave reads a
// contiguous 1 KB segment -> fully coalesced). Sibling blocks (same b,
// consecutive s) cover adjacent frames -> DRAM page locality preserved.
// Writes partial[(s*B + b)*192 + t] unconditionally (ws is poisoned 0xAA).
__global__ __launch_bounds__(192) void partial_kernel(const float* __restrict__ outp,
                                                      const float* __restrict__ lens,
                                                      float* __restrict__ partial) {
    const int b = blockIdx.x;
    const int s = blockIdx.y;
    const int tid = threadIdx.x;  // 0..191
    const int tcount = row_count(lens[b]);

    const float4* base = (const float4*)(outp + (size_t)b * (T_ * D_)) + tid;
    float4 a0 = {0.f, 0.f, 0.f, 0.f}, a1 = a0, a2 = a0, a3 = a0;
    int t = s;
    for (; t + 3 * S_ < tcount; t += 4 * S_) {
        float4 v0 = base[(size_t)t * D4_];
        float4 v1 = base[(size_t)(t + S_) * D4_];
        float4 v2 = base[(size_t)(t + 2 * S_) * D4_];
        float4 v3 = base[(size_t)(t + 3 * S_) * D4_];
        a0.x += v0.x; a0.y += v0.y; a0.z += v0.z; a0.w += v0.w;
        a1.x += v1.x; a1.y += v1.y; a1.z += v1.z; a1.w += v1.w;
        a2.x += v2.x; a2.y += v2.y; a2.z += v2.z; a2.w += v2.w;
        a3.x += v3.x; a3.y += v3.y; a3.z += v3.z; a3.w += v3.w;
    }
    for (; t < tcount; t += S_) {
        float4 v0 = base[(size_t)t * D4_];
        a0.x += v0.x; a0.y += v0.y; a0.z += v0.z; a0.w += v0.w;
    }
    float4 acc;
    acc.x = (a0.x + a1.x) + (a2.x + a3.x);
    acc.y = (a0.y + a1.y) + (a2.y + a3.y);
    acc.z = (a0.z + a1.z) + (a2.z + a3.z);
    acc.w = (a0.w + a1.w) + (a2.w + a3.w);

    float4* p = (float4*)partial + ((size_t)s * B_ + b) * D4_ + tid;
    *p = acc;
}

// ---- Kernel F: fused {global min/max of gnoise} + {reduce S_ partials} +
//      {divide by count} + {add scaled noise} -> out [B, D].
// 48 blocks x 256 threads = 12288 threads = exactly B*D/4 float4 outputs.
// Every block redundantly scans gnoise (192 KB, L2-resident: ~9 MB L2 traffic
// total, ~0.3 us) -- cheaper than a separate kernel + launch.
__global__ __launch_bounds__(256) void finalize_kernel(const float* __restrict__ lens,
                                                       const float* __restrict__ graw,
                                                       const float* __restrict__ partial,
                                                       float* __restrict__ outp) {
    const int tid = threadIdx.x;
    const int idx = blockIdx.x * 256 + tid;  // 0..12287, float4 index over [B, D]

    // --- block-redundant global min/max of gnoise_raw ---
    const float4* g4 = (const float4*)graw;
    float vmin = INFINITY, vmax = -INFINITY;
    for (int i = tid; i < B_ * D4_; i += 256) {  // 48 iters
        float4 v = g4[i];
        vmin = fminf(vmin, fminf(fminf(v.x, v.y), fminf(v.z, v.w)));
        vmax = fmaxf(vmax, fmaxf(fmaxf(v.x, v.y), fmaxf(v.z, v.w)));
    }
    #pragma unroll
    for (int off = 1; off < 64; off <<= 1) {
        vmin = fminf(vmin, __shfl_xor(vmin, off, 64));
        vmax = fmaxf(vmax, __shfl_xor(vmax, off, 64));
    }
    __shared__ float red[8];  // 4 waves: [0..3]=min, [4..7]=max
    const int wave = tid >> 6;
    if ((tid & 63) == 0) { red[wave] = vmin; red[4 + wave] = vmax; }
    __syncthreads();
    vmin = fminf(fminf(red[0], red[1]), fminf(red[2], red[3]));
    vmax = fmaxf(fmaxf(red[4], red[5]), fmaxf(red[6], red[7]));
    const float scale = 1.0f / (vmax - vmin);

    // --- sum the S_ strided partials for this (b, c4) ---
    const int b = idx / D4_;
    const int c4 = idx - b * D4_;
    const float4* p4 = (const float4*)partial;
    float4 acc = {0.f, 0.f, 0.f, 0.f};
    #pragma unroll
    for (int s = 0; s < S_; ++s) {
        float4 v = p4[((size_t)s * B_ + b) * D4_ + c4];
        acc.x += v.x; acc.y += v.y; acc.z += v.z; acc.w += v.w;
    }
    const float inv = 1.0f / (float)row_count(lens[b]);

    // gnoise = EPS * ((1-9)*g + 9), g normalized to [0,1]
    float4 g = g4[idx];
    float4 o;
    o.x = acc.x * inv + EPS_ * (9.0f - 8.0f * ((g.x - vmin) * scale));
    o.y = acc.y * inv + EPS_ * (9.0f - 8.0f * ((g.y - vmin) * scale));
    o.z = acc.z * inv + EPS_ * (9.0f - 8.0f * ((g.z - vmin) * scale));
    o.w = acc.w * inv + EPS_ * (9.0f - 8.0f * ((g.w - vmin) * scale));
    ((float4*)outp)[idx] = o;
}

extern "C" void kernel_launch(void* const* d_in, const int* in_sizes, int n_in,
                              void* d_out, int out_size, void* d_ws, size_t ws_size,
                              hipStream_t stream) {
    const float* outputs = (const float*)d_in[0];   // [B, T, D] fp32
    const float* lens    = (const float*)d_in[1];   // [B] fp32
    const float* graw    = (const float*)d_in[2];   // [B, D] fp32
    float* out = (float*)d_out;                     // [B, 1, D] fp32
    float* partial = (float*)d_ws;                  // S_*B_*D_ floats = 6.3 MB

    partial_kernel<<<dim3(B_, S_), 192, 0, stream>>>(outputs, lens, partial);
    finalize_kernel<<<48, 256, 0, stream>>>(lens, graw, partial, out);
}